// Round 12
// baseline (380.488 us; speedup 1.0000x reference)
//
#include <hip/hip_runtime.h>
#include <hip/hip_bf16.h>

typedef __hip_bfloat16 bf16;
typedef __attribute__((ext_vector_type(8))) short bf16x8;
typedef __attribute__((ext_vector_type(4))) float f32x4;

#define T_DIM 2048
#define B_DIM 8
#define E_DIM 512
#define N_DIM 1024
#define M_ROWS (T_DIM * B_DIM)   // 16384
#define NCHUNK 64
#define CLEN (T_DIM / NCHUNK)    // 32

__device__ __forceinline__ void gload16(const void* g, void* l) {
    __builtin_amdgcn_global_load_lds((const void __attribute__((address_space(1)))*)g,
                                     (void __attribute__((address_space(3)))*)l, 16, 0, 0);
}

// ---------- merged prep + bias vectors (no cross-block deps: exp recomputed) ----------
__global__ void k_prep_bias(const float* __restrict__ nu_log, const float* __restrict__ theta_log,
                            const float* __restrict__ gamma_log, const float* __restrict__ b_in,
                            const float* __restrict__ B_real, const float* __restrict__ B_imag,
                            const float* __restrict__ b_out, const float* __restrict__ Dvec,
                            const float* __restrict__ W_out,
                            float* __restrict__ LamR, float* __restrict__ LamI,
                            float* __restrict__ g, float* __restrict__ c_bu, float* __restrict__ bo) {
    int id = blockIdx.x;  // 84 = 4 (prep) + 64 (c_bu) + 16 (bo)
    if (id < 4) {
        int i = id * 256 + threadIdx.x;
        float nu  = expf(nu_log[i]);
        float th  = expf(theta_log[i]);
        float mag = expf(-nu);
        LamR[i] = mag * cosf(th);
        LamI[i] = mag * sinf(th);
        g[i] = expf(gamma_log[i]);
    } else if (id < 68) {
        int l = id - 4;
        int jblk = l & 7, ic = l >> 3;
        int j = jblk * 256 + threadIdx.x;
        const float* B = (j < N_DIM) ? B_real : B_imag;
        int jj = j & (N_DIM - 1);
        float s = 0.f;
        for (int i = ic * 128; i < ic * 128 + 128; ++i)
            s = fmaf(b_in[i] * expf(gamma_log[i]), B[(size_t)i * N_DIM + jj], s);
        atomicAdd(&c_bu[j], s);
    } else {
        int l = id - 68;
        int eblk = l & 1, ic = l >> 1;
        int e = eblk * 256 + threadIdx.x;
        float s = (ic == 0) ? b_out[e] : 0.f;
        for (int j = ic * 128; j < ic * 128 + 128; ++j)
            s = fmaf(b_in[j] * Dvec[j], W_out[(size_t)j * E_DIM + e], s);
        atomicAdd(&bo[e], s);
    }
}

// ---------- merged fp32->bf16 converts: x, W_in, C_r, -C_i (one launch) ----------
// grid = 10752 = 8192 (x) + 512 (W_in) + 1024 (C_r) + 1024 (C_i)
struct __align__(8) bf4 { bf16 v[4]; };
__global__ void k_conv_all(const float* __restrict__ x, const float* __restrict__ W_in,
                           const float* __restrict__ C_r, const float* __restrict__ C_i,
                           bf16* __restrict__ xb, bf16* __restrict__ Win_b,
                           bf16* __restrict__ Cr_b, bf16* __restrict__ Ci_b) {
    int id = blockIdx.x;
    const float* src; bf16* dst; float mul = 1.f; int base;
    if (id < 8192)      { src = x;    dst = xb;    base = id; }
    else if (id < 8704) { src = W_in; dst = Win_b; base = id - 8192; }
    else if (id < 9728) { src = C_r;  dst = Cr_b;  base = id - 8704; }
    else                { src = C_i;  dst = Ci_b;  base = id - 9728; mul = -1.f; }
    int i = base * 256 + threadIdx.x;
    float4 v = ((const float4*)src)[i];
    bf4 o;
    o.v[0] = __float2bfloat16(v.x * mul);
    o.v[1] = __float2bfloat16(v.y * mul);
    o.v[2] = __float2bfloat16(v.z * mul);
    o.v[3] = __float2bfloat16(v.w * mul);
    ((bf4*)dst)[i] = o;
}

// ---------- merged transposes: B_r*g, B_i*g, W_out, W_out*D (one launch) ----------
__global__ void k_transpose_all(const float* __restrict__ B_r, const float* __restrict__ B_i,
                                const float* __restrict__ W_out, const float* __restrict__ gvec,
                                const float* __restrict__ Dvec,
                                bf16* __restrict__ BscT, bf16* __restrict__ WoT,
                                bf16* __restrict__ WoTD) {
    __shared__ float tile[32][33];
    int id = blockIdx.x;  // 3072 = 1024 + 1024 + 512 + 512
    const float* in; bf16* out; const float* scale; int R, C, bx, by;
    if (id < 1024)      { in = B_r;   out = BscT;                      scale = gvec; R = 1024; C = 1024; bx = id & 31;          by = id >> 5; }
    else if (id < 2048) { int l = id - 1024; in = B_i; out = BscT + (size_t)1024 * 1024; scale = gvec; R = 1024; C = 1024; bx = l & 31; by = l >> 5; }
    else if (id < 2560) { int l = id - 2048; in = W_out; out = WoT;    scale = nullptr; R = 1024; C = 512; bx = l & 15; by = l >> 4; }
    else                { int l = id - 2560; in = W_out; out = WoTD;   scale = Dvec;   R = 1024; C = 512; bx = l & 15; by = l >> 4; }
    int tx = threadIdx.x & 31, ty = threadIdx.x >> 5;
    int r0 = by * 32, c0 = bx * 32;
#pragma unroll
    for (int i = 0; i < 32; i += 8) {
        int r = r0 + ty + i;
        float v = in[(size_t)r * C + c0 + tx];
        if (scale) v *= scale[r];
        tile[ty + i][tx] = v;
    }
    __syncthreads();
#pragma unroll
    for (int i = 0; i < 32; i += 8) {
        out[(size_t)(c0 + ty + i) * R + r0 + tx] = __float2bfloat16(tile[tx][ty + i]);
    }
}

// ---------- shared 128x128 GEMM core, 2-buffer, conflict-free slot swizzle ----------
// Slot permutation: LDS slot s of row rr holds global slot (s - rr - rr/4) & 3;
// read of logical slot fq uses LDS slot (fq + rr + rr/4) & 3. Bank-quad
// (4rr + slot) % 8 then covers all 8 quads exactly twice per 16 lanes -> 2-way
// aliasing = free (m136). Per K-step: stage(next buf) -> ds_read cur ->
// setprio MFMA -> one __syncthreads.
template <bool ASPLIT, bool OUTF32, bool BIAS, bool ATOMIC>
__device__ __forceinline__ void gemm_db_core(bf16* lds,
        const bf16* __restrict__ A0, const bf16* __restrict__ A1, int ksplit,
        int lda0, int lda1, const bf16* __restrict__ Bt, int ldb,
        void* __restrict__ outp, int ldo, const float* __restrict__ bias,
        int kbase, int nt, int bn, int bm) {
    const int tid = threadIdx.x;
    const int lane = tid & 63, w = tid >> 6;
    const int wr = w >> 1, wc = w & 1;
    const int fr = lane & 15, fq = lane >> 4;
    f32x4 acc[4][4] = {};

    auto stage = [&](int buf, int t) {
        int k0 = kbase + t * 32;
        const bf16* Ap = A0; int lda = lda0, ac = k0;
        if (ASPLIT && k0 >= ksplit) { Ap = A1; lda = lda1; ac = k0 - ksplit; }
        bf16* dst = lds + buf * 8192;
#pragma unroll
        for (int L = 0; L < 2; ++L) {
            int idx = L * 256 + tid;
            int rr = idx >> 2, s = idx & 3;
            int kk = ((s - rr - (rr >> 2)) & 3) * 8;   // inverse slot permutation on src
            gload16(Ap + (size_t)(bm * 128 + rr) * lda + ac + kk, dst + idx * 8);
            gload16(Bt + (size_t)(bn * 128 + rr) * ldb + k0 + kk, dst + 4096 + idx * 8);
        }
    };

    stage(0, 0);
    __syncthreads();
    int cur = 0;
    for (int t = 0; t < nt; ++t) {
        if (t + 1 < nt) stage(cur ^ 1, t + 1);     // issue next-tile loads first
        const bf16* bufA = lds + cur * 8192;
        const bf16* bufB = bufA + 4096;
        bf16x8 af[4], bfr[4];
#pragma unroll
        for (int i = 0; i < 4; ++i) {
            int rr = wr * 64 + i * 16 + fr;
            af[i] = *(const bf16x8*)(bufA + (rr * 4 + ((fq + rr + (rr >> 2)) & 3)) * 8);
        }
#pragma unroll
        for (int j = 0; j < 4; ++j) {
            int rr = wc * 64 + j * 16 + fr;
            bfr[j] = *(const bf16x8*)(bufB + (rr * 4 + ((fq + rr + (rr >> 2)) & 3)) * 8);
        }
        __builtin_amdgcn_s_setprio(1);
#pragma unroll
        for (int i = 0; i < 4; ++i)
#pragma unroll
            for (int j = 0; j < 4; ++j)
                acc[i][j] = __builtin_amdgcn_mfma_f32_16x16x32_bf16(af[i], bfr[j], acc[i][j], 0, 0, 0);
        __builtin_amdgcn_s_setprio(0);
        __syncthreads();                            // stage(t+1) complete + reads done
        cur ^= 1;
    }
    const int orow = bm * 128 + wr * 64;
    const int ocol = bn * 128 + wc * 64;
#pragma unroll
    for (int i = 0; i < 4; ++i)
#pragma unroll
        for (int j = 0; j < 4; ++j) {
            int col = ocol + j * 16 + fr;
            float bv = (BIAS && bias) ? bias[col] : 0.0f;
#pragma unroll
            for (int r = 0; r < 4; ++r) {
                int row = orow + i * 16 + fq * 4 + r;
                float v = acc[i][j][r] + bv;
                if (ATOMIC)      atomicAdd((float*)outp + (size_t)row * ldo + col, v);
                else if (OUTF32) ((float*)outp)[(size_t)row * ldo + col] = v;
                else             ((bf16*)outp)[(size_t)row * ldo + col] = __float2bfloat16(v);
            }
        }
}

// ---------- G1: BuH[16384,2048] = xb @ WBcat^T + c_bu, XCD-swizzled ----------
__global__ __launch_bounds__(256)
void k_g1(const bf16* __restrict__ xb, const bf16* __restrict__ WBcat,
          bf16* __restrict__ BuH, const float* __restrict__ c_bu) {
    __shared__ __align__(16) bf16 lds[2 * 8192];
    int id = blockIdx.x;                       // 2048, %8==0 -> bijective chunk swizzle
    int swz = (id & 7) * 256 + (id >> 3);
    int bn = swz & 15, bm = swz >> 4;
    gemm_db_core<false, false, true, false>(lds, xb, nullptr, 0, 512, 0, WBcat, 512,
                                            BuH, 2048, c_bu, 0, 16, bn, bm);
}

// ---------- G2 split-K: out[16384,512] += [h|x] @ Bfin^T (+biasO in half 0) ----------
// grid 1024 = 2 K-halves x 512 tiles; out pre-zeroed; fp32 atomicAdd epilogue.
__global__ __launch_bounds__(256)
void k_g2(const bf16* __restrict__ BuH, const bf16* __restrict__ xb,
          const bf16* __restrict__ Bfin, float* __restrict__ out,
          const float* __restrict__ biasO) {
    __shared__ __align__(16) bf16 lds[2 * 8192];
    int id = blockIdx.x;
    int half = id >> 9;                        // 0: k in [0,1280), 1: [1280,2560)
    int hid = id & 511;                        // %8==0 swizzle within half
    int swz = (hid & 7) * 64 + (hid >> 3);
    int bn = swz & 3, bm = swz >> 2;
    gemm_db_core<true, true, true, true>(lds, BuH, xb, 2048, 2048, 512, Bfin, 2560,
                                         out, 512, half ? nullptr : biasO,
                                         half * 1280, 40, bn, bm);
}

// ---------- batched small precompute GEMMs (one launch, 144 blocks) ----------
__global__ __launch_bounds__(256)
void k_gemm4(const bf16* __restrict__ BscT, const bf16* __restrict__ Win_b,
             const bf16* __restrict__ WoT, const bf16* __restrict__ WoTD,
             const bf16* __restrict__ Cr_b, const bf16* __restrict__ Ci_b,
             bf16* __restrict__ WBcat, bf16* __restrict__ Bfin) {
    __shared__ __align__(16) bf16 lds[2 * 8192];
    int id = blockIdx.x;
    if (id < 64) {        // WBcat[2048,512] = BscT @ Win_b^T
        gemm_db_core<false, false, false, false>(lds, BscT, nullptr, 0, 1024, 0, Win_b, 1024, WBcat, 512, nullptr, 0, 32, id & 3, id >> 2);
    } else if (id < 96) { // Bfin[:, 0:1024) = WoT @ Cr_b^T
        int l = id - 64;
        gemm_db_core<false, false, false, false>(lds, WoT, nullptr, 0, 1024, 0, Cr_b, 1024, Bfin, 2560, nullptr, 0, 32, l & 7, l >> 3);
    } else if (id < 128) {// Bfin[:, 1024:2048) = WoT @ (-Ci)^T
        int l = id - 96;
        gemm_db_core<false, false, false, false>(lds, WoT, nullptr, 0, 1024, 0, Ci_b, 1024, Bfin + 1024, 2560, nullptr, 0, 32, l & 7, l >> 3);
    } else {              // Bfin[:, 2048:2560) = WoTD @ Win_b^T
        int l = id - 128;
        gemm_db_core<false, false, false, false>(lds, WoTD, nullptr, 0, 1024, 0, Win_b, 1024, Bfin + 2048, 2560, nullptr, 0, 32, l & 3, l >> 2);
    }
}

// ---------- chunked linear scan over time ----------
__global__ void k_scan_carry(const bf16* __restrict__ BuH, const float* __restrict__ LamR,
                             const float* __restrict__ LamI, float2* __restrict__ carry) {
    int tid = blockIdx.x * 256 + threadIdx.x;  // [0, NCHUNK*8192)
    int n = tid & (N_DIM - 1);
    int bb = (tid >> 10) & 7;
    int c = tid >> 13;
    float lr = LamR[n], li = LamI[n];
    float hr = 0.f, hi = 0.f;
    const bf16* p = BuH + ((size_t)(c * CLEN) * B_DIM + bb) * 2048 + n;
#pragma unroll 8
    for (int t = 0; t < CLEN; ++t) {
        float br = __bfloat162float(p[0]);
        float bi = __bfloat162float(p[N_DIM]);
        float nr = fmaf(lr, hr, fmaf(-li, hi, br));
        float ni = fmaf(lr, hi, fmaf(li, hr, bi));
        hr = nr; hi = ni;
        p += B_DIM * 2048;
    }
    carry[tid] = make_float2(hr, hi);
}

__global__ void k_scan_combine(const float2* __restrict__ carry, float2* __restrict__ S,
                               const float* __restrict__ LamR, const float* __restrict__ LamI) {
    int tid = blockIdx.x * 256 + threadIdx.x;  // [0, 8192)
    int n = tid & (N_DIM - 1);
    float ar = LamR[n], ai = LamI[n];
#pragma unroll
    for (int s = 0; s < 5; ++s) { float nr = ar * ar - ai * ai, ni = 2.f * ar * ai; ar = nr; ai = ni; }  // Lam^32
    float sr = 0.f, si = 0.f;
    for (int c = 0; c < NCHUNK; ++c) {
        S[(size_t)c * 8192 + tid] = make_float2(sr, si);
        float2 ca = carry[(size_t)c * 8192 + tid];
        float nr = fmaf(ar, sr, fmaf(-ai, si, ca.x));
        float ni = fmaf(ar, si, fmaf(ai, sr, ca.y));
        sr = nr; si = ni;
    }
}

__global__ void k_scan_apply(bf16* __restrict__ BuH, const float* __restrict__ LamR,
                             const float* __restrict__ LamI, const float2* __restrict__ S) {
    int tid = blockIdx.x * 256 + threadIdx.x;
    int n = tid & (N_DIM - 1);
    int bb = (tid >> 10) & 7;
    int c = tid >> 13;
    float lr = LamR[n], li = LamI[n];
    float2 s0 = S[tid];
    float hr = s0.x, hi = s0.y;
    bf16* p = BuH + ((size_t)(c * CLEN) * B_DIM + bb) * 2048 + n;
#pragma unroll 8
    for (int t = 0; t < CLEN; ++t) {
        float br = __bfloat162float(p[0]);
        float bi = __bfloat162float(p[N_DIM]);
        float nr = fmaf(lr, hr, fmaf(-li, hi, br));
        float ni = fmaf(lr, hi, fmaf(li, hr, bi));
        hr = nr; hi = ni;
        p[0] = __float2bfloat16(hr);
        p[N_DIM] = __float2bfloat16(hi);
        p += B_DIM * 2048;
    }
}

extern "C" void kernel_launch(void* const* d_in, const int* in_sizes, int n_in,
                              void* d_out, int out_size, void* d_ws, size_t ws_size,
                              hipStream_t stream) {
    const float* x         = (const float*)d_in[0];
    const float* W_in      = (const float*)d_in[1];
    const float* b_in      = (const float*)d_in[2];
    const float* W_out     = (const float*)d_in[3];
    const float* b_out     = (const float*)d_in[4];
    const float* nu_log    = (const float*)d_in[5];
    const float* theta_log = (const float*)d_in[6];
    const float* gamma_log = (const float*)d_in[7];
    const float* B_real    = (const float*)d_in[8];
    const float* B_imag    = (const float*)d_in[9];
    const float* C_real    = (const float*)d_in[10];
    const float* C_imag    = (const float*)d_in[11];
    const float* Dvec      = (const float*)d_in[12];
    float* out = (float*)d_out;

    char* ws = (char*)d_ws;
    size_t off = 0;
    auto alloc = [&](size_t bytes) { void* p = ws + off; off = (off + bytes + 255) & ~(size_t)255; return p; };
    bf16*  xb    = (bf16*)alloc((size_t)M_ROWS * E_DIM * 2);
    bf16*  BuH   = (bf16*)alloc((size_t)M_ROWS * 2048 * 2);
    bf16*  BscT  = (bf16*)alloc((size_t)2048 * 1024 * 2);
    bf16*  Win_b = (bf16*)alloc((size_t)512 * 1024 * 2);
    bf16*  Cr_b  = (bf16*)alloc((size_t)1024 * 1024 * 2);
    bf16*  Ci_b  = (bf16*)alloc((size_t)1024 * 1024 * 2);
    bf16*  WoT   = (bf16*)alloc((size_t)512 * 1024 * 2);
    bf16*  WoTD  = (bf16*)alloc((size_t)512 * 1024 * 2);
    bf16*  WBcat = (bf16*)alloc((size_t)2048 * 512 * 2);
    bf16*  Bfin  = (bf16*)alloc((size_t)512 * 2560 * 2);
    float* LamR  = (float*)alloc(1024 * 4);
    float* LamI  = (float*)alloc(1024 * 4);
    float* gvec  = (float*)alloc(1024 * 4);
    float* c_bu  = (float*)alloc(2048 * 4);
    float* biasO = (float*)alloc(512 * 4);
    float2* carry = (float2*)alloc((size_t)NCHUNK * 8192 * 8);
    float2* Sbuf  = (float2*)alloc((size_t)NCHUNK * 8192 * 8);

    // zero accumulation targets (ws/out are re-poisoned 0xAA before every call)
    hipMemsetAsync(c_bu, 0, 2048 * 4, stream);
    hipMemsetAsync(biasO, 0, 512 * 4, stream);
    hipMemsetAsync(out, 0, (size_t)M_ROWS * E_DIM * 4, stream);

    // prep + bias (one launch), merged converts/transposes
    k_prep_bias<<<84, 256, 0, stream>>>(nu_log, theta_log, gamma_log, b_in, B_real, B_imag,
                                        b_out, Dvec, W_out, LamR, LamI, gvec, c_bu, biasO);
    k_conv_all<<<10752, 256, 0, stream>>>(x, W_in, C_real, C_imag, xb, Win_b, Cr_b, Ci_b);
    k_transpose_all<<<3072, 256, 0, stream>>>(B_real, B_imag, W_out, gvec, Dvec, BscT, WoT, WoTD);

    // precompute folds: one batched launch (144 blocks)
    k_gemm4<<<144, 256, 0, stream>>>(BscT, Win_b, WoT, WoTD, Cr_b, Ci_b, WBcat, Bfin);

    // G1: BuH[16384,2048] = xb @ WBcat^T + c_bu   (Bu real|imag)
    k_g1<<<2048, 256, 0, stream>>>(xb, WBcat, BuH, c_bu);

    // scan: h_t = Lam*h_{t-1} + Bu_t  (in place, bf16 out)
    k_scan_carry<<<NCHUNK * 8192 / 256, 256, 0, stream>>>(BuH, LamR, LamI, carry);
    k_scan_combine<<<32, 256, 0, stream>>>(carry, Sbuf, LamR, LamI);
    k_scan_apply<<<NCHUNK * 8192 / 256, 256, 0, stream>>>(BuH, LamR, LamI, Sbuf);

    // G2 split-K: out += [h|x] @ Bfin^T (+biasO in half 0), atomic f32 epilogue
    k_g2<<<1024, 256, 0, stream>>>(BuH, xb, Bfin, out, biasO);
}

// Round 13
// 333.507 us; speedup vs baseline: 1.1409x; 1.1409x over previous
//
#include <hip/hip_runtime.h>
#include <hip/hip_bf16.h>

typedef __hip_bfloat16 bf16;
typedef __attribute__((ext_vector_type(8))) short bf16x8;
typedef __attribute__((ext_vector_type(4))) float f32x4;

#define T_DIM 2048
#define B_DIM 8
#define E_DIM 512
#define N_DIM 1024
#define M_ROWS (T_DIM * B_DIM)   // 16384
#define NCHUNK 64
#define CLEN (T_DIM / NCHUNK)    // 32

__device__ __forceinline__ void gload16(const void* g, void* l) {
    __builtin_amdgcn_global_load_lds((const void __attribute__((address_space(1)))*)g,
                                     (void __attribute__((address_space(3)))*)l, 16, 0, 0);
}
__device__ __forceinline__ float bf2f(short s) {
    return __uint_as_float(((unsigned)(unsigned short)s) << 16);
}
__device__ __forceinline__ short f2bf(float f) {
    bf16 h = __float2bfloat16(f);
    return *reinterpret_cast<short*>(&h);
}

// ---------- merged prep + bias vectors ----------
__global__ void k_prep_bias(const float* __restrict__ nu_log, const float* __restrict__ theta_log,
                            const float* __restrict__ gamma_log, const float* __restrict__ b_in,
                            const float* __restrict__ B_real, const float* __restrict__ B_imag,
                            const float* __restrict__ b_out, const float* __restrict__ Dvec,
                            const float* __restrict__ W_out,
                            float* __restrict__ LamR, float* __restrict__ LamI,
                            float* __restrict__ g, float* __restrict__ c_bu, float* __restrict__ bo) {
    int id = blockIdx.x;  // 84 = 4 (prep) + 64 (c_bu) + 16 (bo)
    if (id < 4) {
        int i = id * 256 + threadIdx.x;
        float nu  = expf(nu_log[i]);
        float th  = expf(theta_log[i]);
        float mag = expf(-nu);
        LamR[i] = mag * cosf(th);
        LamI[i] = mag * sinf(th);
        g[i] = expf(gamma_log[i]);
    } else if (id < 68) {
        int l = id - 4;
        int jblk = l & 7, ic = l >> 3;
        int j = jblk * 256 + threadIdx.x;
        const float* B = (j < N_DIM) ? B_real : B_imag;
        int jj = j & (N_DIM - 1);
        float s = 0.f;
        for (int i = ic * 128; i < ic * 128 + 128; ++i)
            s = fmaf(b_in[i] * expf(gamma_log[i]), B[(size_t)i * N_DIM + jj], s);
        atomicAdd(&c_bu[j], s);
    } else {
        int l = id - 68;
        int eblk = l & 1, ic = l >> 1;
        int e = eblk * 256 + threadIdx.x;
        float s = (ic == 0) ? b_out[e] : 0.f;
        for (int j = ic * 128; j < ic * 128 + 128; ++j)
            s = fmaf(b_in[j] * Dvec[j], W_out[(size_t)j * E_DIM + e], s);
        atomicAdd(&bo[e], s);
    }
}

// ---------- merged fp32->bf16 converts: x, W_in, C_r, -C_i ----------
struct __align__(8) bf4 { bf16 v[4]; };
__global__ void k_conv_all(const float* __restrict__ x, const float* __restrict__ W_in,
                           const float* __restrict__ C_r, const float* __restrict__ C_i,
                           bf16* __restrict__ xb, bf16* __restrict__ Win_b,
                           bf16* __restrict__ Cr_b, bf16* __restrict__ Ci_b) {
    int id = blockIdx.x;  // 10752 = 8192 + 512 + 1024 + 1024
    const float* src; bf16* dst; float mul = 1.f; int base;
    if (id < 8192)      { src = x;    dst = xb;    base = id; }
    else if (id < 8704) { src = W_in; dst = Win_b; base = id - 8192; }
    else if (id < 9728) { src = C_r;  dst = Cr_b;  base = id - 8704; }
    else                { src = C_i;  dst = Ci_b;  base = id - 9728; mul = -1.f; }
    int i = base * 256 + threadIdx.x;
    float4 v = ((const float4*)src)[i];
    bf4 o;
    o.v[0] = __float2bfloat16(v.x * mul);
    o.v[1] = __float2bfloat16(v.y * mul);
    o.v[2] = __float2bfloat16(v.z * mul);
    o.v[3] = __float2bfloat16(v.w * mul);
    ((bf4*)dst)[i] = o;
}

// ---------- merged transposes: B_r*g, B_i*g, W_out, W_out*D ----------
__global__ void k_transpose_all(const float* __restrict__ B_r, const float* __restrict__ B_i,
                                const float* __restrict__ W_out, const float* __restrict__ gvec,
                                const float* __restrict__ Dvec,
                                bf16* __restrict__ BscT, bf16* __restrict__ WoT,
                                bf16* __restrict__ WoTD) {
    __shared__ float tile[32][33];
    int id = blockIdx.x;  // 3072 = 1024 + 1024 + 512 + 512
    const float* in; bf16* out; const float* scale; int R, C, bx, by;
    if (id < 1024)      { in = B_r;   out = BscT;                      scale = gvec; R = 1024; C = 1024; bx = id & 31;          by = id >> 5; }
    else if (id < 2048) { int l = id - 1024; in = B_i; out = BscT + (size_t)1024 * 1024; scale = gvec; R = 1024; C = 1024; bx = l & 31; by = l >> 5; }
    else if (id < 2560) { int l = id - 2048; in = W_out; out = WoT;    scale = nullptr; R = 1024; C = 512; bx = l & 15; by = l >> 4; }
    else                { int l = id - 2560; in = W_out; out = WoTD;   scale = Dvec;   R = 1024; C = 512; bx = l & 15; by = l >> 4; }
    int tx = threadIdx.x & 31, ty = threadIdx.x >> 5;
    int r0 = by * 32, c0 = bx * 32;
#pragma unroll
    for (int i = 0; i < 32; i += 8) {
        int r = r0 + ty + i;
        float v = in[(size_t)r * C + c0 + tx];
        if (scale) v *= scale[r];
        tile[ty + i][tx] = v;
    }
    __syncthreads();
#pragma unroll
    for (int i = 0; i < 32; i += 8) {
        out[(size_t)(c0 + ty + i) * R + r0 + tx] = __float2bfloat16(tile[tx][ty + i]);
    }
}

// ---------- shared 128x128 GEMM core, 2-buffer (round-10 structure) ----------
template <bool ASPLIT, bool OUTF32, bool BIAS>
__device__ __forceinline__ void gemm_db_core(bf16* lds,
        const bf16* __restrict__ A0, const bf16* __restrict__ A1, int ksplit,
        int lda0, int lda1, const bf16* __restrict__ Bt, int ldb,
        void* __restrict__ outp, int ldo, const float* __restrict__ bias,
        int nt, int bn, int bm) {
    const int tid = threadIdx.x;
    const int lane = tid & 63, w = tid >> 6;
    const int wr = w >> 1, wc = w & 1;
    const int fr = lane & 15, fq = lane >> 4;
    f32x4 acc[4][4] = {};

    auto stage = [&](int buf, int t) {
        int k0 = t * 32;
        const bf16* Ap = A0; int lda = lda0, ac = k0;
        if (ASPLIT && k0 >= ksplit) { Ap = A1; lda = lda1; ac = k0 - ksplit; }
        bf16* dst = lds + buf * 8192;
#pragma unroll
        for (int L = 0; L < 2; ++L) {
            int idx = L * 256 + tid;
            int rr = idx >> 2, s = idx & 3;
            int kk = ((s - rr - (rr >> 2)) & 3) * 8;   // inverse slot permutation on src
            gload16(Ap + (size_t)(bm * 128 + rr) * lda + ac + kk, dst + idx * 8);
            gload16(Bt + (size_t)(bn * 128 + rr) * ldb + k0 + kk, dst + 4096 + idx * 8);
        }
    };

    stage(0, 0);
    __syncthreads();
    int cur = 0;
    for (int t = 0; t < nt; ++t) {
        if (t + 1 < nt) stage(cur ^ 1, t + 1);     // issue next-tile loads first
        const bf16* bufA = lds + cur * 8192;
        const bf16* bufB = bufA + 4096;
        bf16x8 af[4], bfr[4];
#pragma unroll
        for (int i = 0; i < 4; ++i) {
            int rr = wr * 64 + i * 16 + fr;
            af[i] = *(const bf16x8*)(bufA + (rr * 4 + ((fq + rr + (rr >> 2)) & 3)) * 8);
        }
#pragma unroll
        for (int j = 0; j < 4; ++j) {
            int rr = wc * 64 + j * 16 + fr;
            bfr[j] = *(const bf16x8*)(bufB + (rr * 4 + ((fq + rr + (rr >> 2)) & 3)) * 8);
        }
        __builtin_amdgcn_s_setprio(1);
#pragma unroll
        for (int i = 0; i < 4; ++i)
#pragma unroll
            for (int j = 0; j < 4; ++j)
                acc[i][j] = __builtin_amdgcn_mfma_f32_16x16x32_bf16(af[i], bfr[j], acc[i][j], 0, 0, 0);
        __builtin_amdgcn_s_setprio(0);
        __syncthreads();                            // stage(t+1) complete + reads done
        cur ^= 1;
    }
    const int orow = bm * 128 + wr * 64;
    const int ocol = bn * 128 + wc * 64;
#pragma unroll
    for (int i = 0; i < 4; ++i)
#pragma unroll
        for (int j = 0; j < 4; ++j) {
            int col = ocol + j * 16 + fr;
            float bv = BIAS ? bias[col] : 0.0f;
#pragma unroll
            for (int r = 0; r < 4; ++r) {
                int row = orow + i * 16 + fq * 4 + r;
                float v = acc[i][j][r] + bv;
                if (OUTF32) ((float*)outp)[(size_t)row * ldo + col] = v;
                else        ((bf16*)outp)[(size_t)row * ldo + col] = __float2bfloat16(v);
            }
        }
}

// ---------- G1: BuH[16384,2048] = xb @ WBcat^T + c_bu, XCD-swizzled ----------
__global__ __launch_bounds__(256)
void k_g1(const bf16* __restrict__ xb, const bf16* __restrict__ WBcat,
          bf16* __restrict__ BuH, const float* __restrict__ c_bu) {
    __shared__ __align__(16) bf16 lds[2 * 8192];
    int id = blockIdx.x;                       // 2048, %8==0 -> bijective chunk swizzle
    int swz = (id & 7) * 256 + (id >> 3);
    int bn = swz & 15, bm = swz >> 4;
    gemm_db_core<false, false, true>(lds, xb, nullptr, 0, 512, 0, WBcat, 512,
                                     BuH, 2048, c_bu, 16, bn, bm);
}

// ---------- G2: out[16384,512] = [h_r|h_i|xb] @ Bfin^T + biasO ----------
__global__ __launch_bounds__(256)
void k_g2(const bf16* __restrict__ BuH, const bf16* __restrict__ xb,
          const bf16* __restrict__ Bfin, float* __restrict__ out,
          const float* __restrict__ biasO) {
    __shared__ __align__(16) bf16 lds[2 * 8192];
    int id = blockIdx.x;                       // 512 = 128 bm x 4 bn, %8==0 swizzle
    int swz = (id & 7) * 64 + (id >> 3);
    int bn = swz & 3, bm = swz >> 2;
    gemm_db_core<true, true, true>(lds, BuH, xb, 2048, 2048, 512, Bfin, 2560,
                                   out, 512, biasO, 80, bn, bm);
}

// ---------- batched small precompute GEMMs (one launch, 144 blocks) ----------
__global__ __launch_bounds__(256)
void k_gemm4(const bf16* __restrict__ BscT, const bf16* __restrict__ Win_b,
             const bf16* __restrict__ WoT, const bf16* __restrict__ WoTD,
             const bf16* __restrict__ Cr_b, const bf16* __restrict__ Ci_b,
             bf16* __restrict__ WBcat, bf16* __restrict__ Bfin) {
    __shared__ __align__(16) bf16 lds[2 * 8192];
    int id = blockIdx.x;
    if (id < 64) {        // WBcat[2048,512] = BscT @ Win_b^T
        gemm_db_core<false, false, false>(lds, BscT, nullptr, 0, 1024, 0, Win_b, 1024, WBcat, 512, nullptr, 32, id & 3, id >> 2);
    } else if (id < 96) { // Bfin[:, 0:1024) = WoT @ Cr_b^T
        int l = id - 64;
        gemm_db_core<false, false, false>(lds, WoT, nullptr, 0, 1024, 0, Cr_b, 1024, Bfin, 2560, nullptr, 32, l & 7, l >> 3);
    } else if (id < 128) {// Bfin[:, 1024:2048) = WoT @ (-Ci)^T
        int l = id - 96;
        gemm_db_core<false, false, false>(lds, WoT, nullptr, 0, 1024, 0, Ci_b, 1024, Bfin + 1024, 2560, nullptr, 32, l & 7, l >> 3);
    } else {              // Bfin[:, 2048:2560) = WoTD @ Win_b^T
        int l = id - 128;
        gemm_db_core<false, false, false>(lds, WoTD, nullptr, 0, 1024, 0, Win_b, 1024, Bfin + 2048, 2560, nullptr, 32, l & 3, l >> 2);
    }
}

// ---------- chunked linear scan, bf16x8-vectorized (G13) ----------
// Thread handles 8 consecutive n. tid: ng = tid&127, bb = (tid>>7)&7, c = tid>>10.
__global__ void k_scan_carry(const bf16* __restrict__ BuH, const float* __restrict__ LamR,
                             const float* __restrict__ LamI, float2* __restrict__ carry) {
    int tid = blockIdx.x * 256 + threadIdx.x;  // [0, 65536)
    int ng = tid & 127, bb = (tid >> 7) & 7, c = tid >> 10;
    int n0 = ng * 8;
    float lr[8], li[8], hr[8], hi[8];
#pragma unroll
    for (int j = 0; j < 8; ++j) { lr[j] = LamR[n0 + j]; li[j] = LamI[n0 + j]; hr[j] = 0.f; hi[j] = 0.f; }
    const bf16* p = BuH + ((size_t)(c * CLEN) * B_DIM + bb) * 2048 + n0;
    for (int t = 0; t < CLEN; ++t) {
        bf16x8 re = *(const bf16x8*)(p);
        bf16x8 im = *(const bf16x8*)(p + N_DIM);
#pragma unroll
        for (int j = 0; j < 8; ++j) {
            float br = bf2f(re[j]), bi = bf2f(im[j]);
            float nr = fmaf(lr[j], hr[j], fmaf(-li[j], hi[j], br));
            float ni = fmaf(lr[j], hi[j], fmaf(li[j], hr[j], bi));
            hr[j] = nr; hi[j] = ni;
        }
        p += B_DIM * 2048;
    }
    float2* cp = carry + (size_t)c * 8192 + bb * 1024 + n0;
#pragma unroll
    for (int j = 0; j < 8; ++j) cp[j] = make_float2(hr[j], hi[j]);
}

__global__ void k_scan_combine(const float2* __restrict__ carry, float2* __restrict__ S,
                               const float* __restrict__ LamR, const float* __restrict__ LamI) {
    int tid = blockIdx.x * 256 + threadIdx.x;  // [0, 8192)
    int n = tid & (N_DIM - 1);
    float ar = LamR[n], ai = LamI[n];
#pragma unroll
    for (int s = 0; s < 5; ++s) { float nr = ar * ar - ai * ai, ni = 2.f * ar * ai; ar = nr; ai = ni; }  // Lam^32
    float sr = 0.f, si = 0.f;
    for (int c = 0; c < NCHUNK; ++c) {
        S[(size_t)c * 8192 + tid] = make_float2(sr, si);
        float2 ca = carry[(size_t)c * 8192 + tid];
        float nr = fmaf(ar, sr, fmaf(-ai, si, ca.x));
        float ni = fmaf(ar, si, fmaf(ai, sr, ca.y));
        sr = nr; si = ni;
    }
}

__global__ void k_scan_apply(bf16* __restrict__ BuH, const float* __restrict__ LamR,
                             const float* __restrict__ LamI, const float2* __restrict__ S) {
    int tid = blockIdx.x * 256 + threadIdx.x;  // [0, 65536)
    int ng = tid & 127, bb = (tid >> 7) & 7, c = tid >> 10;
    int n0 = ng * 8;
    float lr[8], li[8], hr[8], hi[8];
    const float2* sp = S + (size_t)c * 8192 + bb * 1024 + n0;
#pragma unroll
    for (int j = 0; j < 8; ++j) {
        lr[j] = LamR[n0 + j]; li[j] = LamI[n0 + j];
        float2 s0 = sp[j]; hr[j] = s0.x; hi[j] = s0.y;
    }
    bf16* p = BuH + ((size_t)(c * CLEN) * B_DIM + bb) * 2048 + n0;
    for (int t = 0; t < CLEN; ++t) {
        bf16x8 re = *(const bf16x8*)(p);
        bf16x8 im = *(const bf16x8*)(p + N_DIM);
        bf16x8 ro, io;
#pragma unroll
        for (int j = 0; j < 8; ++j) {
            float br = bf2f(re[j]), bi = bf2f(im[j]);
            float nr = fmaf(lr[j], hr[j], fmaf(-li[j], hi[j], br));
            float ni = fmaf(lr[j], hi[j], fmaf(li[j], hr[j], bi));
            hr[j] = nr; hi[j] = ni;
            ro[j] = f2bf(nr); io[j] = f2bf(ni);
        }
        *(bf16x8*)(p) = ro;
        *(bf16x8*)(p + N_DIM) = io;
        p += B_DIM * 2048;
    }
}

extern "C" void kernel_launch(void* const* d_in, const int* in_sizes, int n_in,
                              void* d_out, int out_size, void* d_ws, size_t ws_size,
                              hipStream_t stream) {
    const float* x         = (const float*)d_in[0];
    const float* W_in      = (const float*)d_in[1];
    const float* b_in      = (const float*)d_in[2];
    const float* W_out     = (const float*)d_in[3];
    const float* b_out     = (const float*)d_in[4];
    const float* nu_log    = (const float*)d_in[5];
    const float* theta_log = (const float*)d_in[6];
    const float* gamma_log = (const float*)d_in[7];
    const float* B_real    = (const float*)d_in[8];
    const float* B_imag    = (const float*)d_in[9];
    const float* C_real    = (const float*)d_in[10];
    const float* C_imag    = (const float*)d_in[11];
    const float* Dvec      = (const float*)d_in[12];
    float* out = (float*)d_out;

    char* ws = (char*)d_ws;
    size_t off = 0;
    auto alloc = [&](size_t bytes) { void* p = ws + off; off = (off + bytes + 255) & ~(size_t)255; return p; };
    bf16*  xb    = (bf16*)alloc((size_t)M_ROWS * E_DIM * 2);
    bf16*  BuH   = (bf16*)alloc((size_t)M_ROWS * 2048 * 2);
    bf16*  BscT  = (bf16*)alloc((size_t)2048 * 1024 * 2);
    bf16*  Win_b = (bf16*)alloc((size_t)512 * 1024 * 2);
    bf16*  Cr_b  = (bf16*)alloc((size_t)1024 * 1024 * 2);
    bf16*  Ci_b  = (bf16*)alloc((size_t)1024 * 1024 * 2);
    bf16*  WoT   = (bf16*)alloc((size_t)512 * 1024 * 2);
    bf16*  WoTD  = (bf16*)alloc((size_t)512 * 1024 * 2);
    bf16*  WBcat = (bf16*)alloc((size_t)2048 * 512 * 2);
    bf16*  Bfin  = (bf16*)alloc((size_t)512 * 2560 * 2);
    float* LamR  = (float*)alloc(1024 * 4);
    float* LamI  = (float*)alloc(1024 * 4);
    float* gvec  = (float*)alloc(1024 * 4);
    float* c_bu  = (float*)alloc(2048 * 4);
    float* biasO = (float*)alloc(512 * 4);
    float2* carry = (float2*)alloc((size_t)NCHUNK * 8192 * 8);
    float2* Sbuf  = (float2*)alloc((size_t)NCHUNK * 8192 * 8);

    // zero atomic targets (ws is re-poisoned 0xAA before every call)
    hipMemsetAsync(c_bu, 0, 2048 * 4, stream);
    hipMemsetAsync(biasO, 0, 512 * 4, stream);

    // prep + bias (one launch), merged converts/transposes
    k_prep_bias<<<84, 256, 0, stream>>>(nu_log, theta_log, gamma_log, b_in, B_real, B_imag,
                                        b_out, Dvec, W_out, LamR, LamI, gvec, c_bu, biasO);
    k_conv_all<<<10752, 256, 0, stream>>>(x, W_in, C_real, C_imag, xb, Win_b, Cr_b, Ci_b);
    k_transpose_all<<<3072, 256, 0, stream>>>(B_real, B_imag, W_out, gvec, Dvec, BscT, WoT, WoTD);

    // precompute folds: one batched launch (144 blocks)
    k_gemm4<<<144, 256, 0, stream>>>(BscT, Win_b, WoT, WoTD, Cr_b, Ci_b, WBcat, Bfin);

    // G1: BuH[16384,2048] = xb @ WBcat^T + c_bu   (Bu real|imag)
    k_g1<<<2048, 256, 0, stream>>>(xb, WBcat, BuH, c_bu);

    // scan: h_t = Lam*h_{t-1} + Bu_t  (in place, bf16, vectorized x8)
    k_scan_carry<<<256, 256, 0, stream>>>(BuH, LamR, LamI, carry);
    k_scan_combine<<<32, 256, 0, stream>>>(carry, Sbuf, LamR, LamI);
    k_scan_apply<<<256, 256, 0, stream>>>(BuH, LamR, LamI, Sbuf);

    // G2: out[16384,512] = [h_r|h_i|xb] @ Bfin^T + biasO
    k_g2<<<512, 256, 0, stream>>>(BuH, xb, Bfin, out, biasO);
}